// Round 7
// baseline (303.796 us; speedup 1.0000x reference)
//
#include <hip/hip_runtime.h>
#include <math.h>

// Problem constants
#define BHN    55392           // B*H*N = 8*12*577 tokens; 55392 = 4 * 13848
#define NTOK   577
#define HD     64
#define EPS_F  1e-6f
#define NBLOCKS (BHN / 4)      // 4 waves/block, 1 wave = 1 token-row

#if __has_builtin(__builtin_amdgcn_exp2f)
#define EXP2F __builtin_amdgcn_exp2f
#else
#define EXP2F exp2f
#endif

// ---------------------------------------------------------------------------
// Fused kernel, v2: ONE WAVE = ONE TOKEN-ROW (coefs wave-uniform).
//
// R6 post-mortem: 4-rows-per-block phase 2 was VALU-bound (76% busy, 25% HBM)
// on per-element row-select: 12 cndmask cf-select + 3 cmp + segment magic-div
// ~= 3x the essential math. Making coefs wave-uniform deletes all of it.
//
// Phase 1 (per wave, no LDS/sync): lane t computes h_t = dot(q_row, W1[:,t])
//   (q_row wave-uniform -> s_loads; W1 column coalesced), gelu (A&S erf),
//   partial s = g*W2_row, 64-lane butterfly reduce -> ALL lanes hold s0,s1,s2;
//   every lane redundantly computes a,b,c (pre-scaled by log2(e) so phase 2
//   uses exp2 directly), ri, ci.
// Phase 2: lane l handles j = step*64 + l, 9 steps (j=0..575) + lane-0
//   epilogue (j=576). u: normal dword loads (L3-resident from restore —
//   R6 FETCH=70.8MB<128MB proved it; NT loads would forfeit that).
//   out: nontemporal stores (never re-read; don't evict u from L3).
//
// Math identities (validated R1-R6, absmax 0.0039):
//   rowmax(kernel)==1 structurally -> probs = clip(exp(w), eps, 1-eps);
//   sigmoid((logits+noise)/0.1) = 1/(1 + r^10), r = (1-p)(1-u)/(p u),
//   r^10 by squaring; inf/0 saturation gives the correct limits.
// ---------------------------------------------------------------------------
__global__ __launch_bounds__(256) void fused_mask_kernel(
    const float* __restrict__ q,  const float* __restrict__ W1,
    const float* __restrict__ b1, const float* __restrict__ W2,
    const float* __restrict__ b2, const float* __restrict__ u,
    float* __restrict__ out)
{
    const int tid  = threadIdx.x;
    const int lane = tid & 63;
    const int tok  = blockIdx.x * 4 + (tid >> 6);   // exact: grid*4 == BHN

    // ---------------- Phase 1: per-wave MLP ----------------
    const float* qrow = q + (size_t)tok * HD;       // wave-uniform -> s_loads
    float h = 0.0f;
    #pragma unroll 8
    for (int k = 0; k < HD; ++k)
        h = fmaf(qrow[k], W1[k * HD + lane], h);    // coalesced W1 column

    float x = h + b1[lane];
    // gelu, erf via A&S 7.1.26 (|err|<=1.5e-7), branchless
    float z  = x * 0.70710678118654752f;
    float az = fabsf(z);
    float kk = __builtin_amdgcn_rcpf(fmaf(0.3275911f, az, 1.0f));
    float poly = kk * (0.254829592f + kk * (-0.284496736f +
                 kk * (1.421413741f + kk * (-1.453152027f +
                 kk * 1.061405429f))));
    float om   = poly * __expf(-z * z);             // 1 - erf(|z|)
    float erfz = copysignf(1.0f - om, z);
    float g = 0.5f * x * (1.0f + erfz);

    float s0 = g * W2[lane * 3 + 0];
    float s1 = g * W2[lane * 3 + 1];
    float s2 = g * W2[lane * 3 + 2];

    // 64-lane butterfly reduce -> full sum in EVERY lane (no LDS, no sync)
    #pragma unroll
    for (int off = 1; off < 64; off <<= 1) {
        s0 += __shfl_xor(s0, off);
        s1 += __shfl_xor(s1, off);
        s2 += __shfl_xor(s2, off);
    }
    s0 += b2[0]; s1 += b2[1]; s2 += b2[2];

    // covariance tail, redundantly in all lanes (wave-uniform values)
    float sx = fmaxf(s0, 0.0f) + 1.0f;
    float sy = fmaxf(s1, 0.0f) + 1.0f;
    float ex = __expf(2.0f * s2);                   // tanh via exp
    float rho = 0.99f * ((ex - 1.0f) * __builtin_amdgcn_rcpf(ex + 1.0f));
    float sxx = sx * sx, syy = sy * sy;
    float sxy = rho * sx * sy;
    float det = sxx * syy - sxy * sxy;              // >= 0.0199
    float inv_s = 1.4426950408889634f / det;        // fold log2(e): use exp2

    float ca = -0.5f * syy * inv_s;                 // w' = log2-domain quad form
    float cb =  sxy * inv_s;
    float cc = -0.5f * sxx * inv_s;

    const int i = tok % NTOK;
    float rif, cif;
    if (i == 0) {                                   // CLS row: w == 0
        ca = 0.0f; cb = 0.0f; cc = 0.0f; rif = 0.0f; cif = 0.0f;
    } else {
        int ip = i - 1;
        int ri = ip / 24;
        int ci = ip - ri * 24;
        rif = (float)ri; cif = (float)ci;
    }

    // ---------------- Phase 2: this wave's 577-element row ----------------
    const float* urow = u   + (size_t)tok * NTOK;
    float*       orow = out + (size_t)tok * NTOK;

    int j = lane;
    #pragma unroll 1
    for (int step = 0; step < 9; ++step, j += 64) { // j in [0, 576)
        float uk = urow[j];

        unsigned jj = (unsigned)(j - 1);            // j==0 -> garbage, masked
        unsigned rj = jj / 24u;                     // magic-div
        unsigned cj = jj - rj * 24u;
        float dx = rif - (float)rj;
        float dy = cif - (float)cj;
        if (j == 0) { dx = 0.0f; dy = 0.0f; }       // 2 cndmasks

        // w' = ca*dx^2 + cb*dx*dy + cc*dy^2  (log2 domain, <= 0)
        float w = fmaf(fmaf(ca, dx, cb * dy), dx, cc * (dy * dy));

        float p = EXP2F(w);
        p = fminf(fmaxf(p, EPS_F), 1.0f - EPS_F);

        float num = p * uk;                         // >= 1e-12
        float den = (1.0f - p) * (1.0f - uk);
        float r   = den * __builtin_amdgcn_rcpf(num);

        float r2  = r * r;
        float r4  = r2 * r2;
        float r5  = r4 * r;
        float r10 = r5 * r5;                        // inf/0 limits correct

        float res = __builtin_amdgcn_rcpf(1.0f + r10);
        __builtin_nontemporal_store(res, &orow[j]);
    }

    if (lane == 0) {                                // epilogue: j = 576
        float uk = urow[576];
        unsigned jj = 575u;
        unsigned rj = jj / 24u;                     // 23
        unsigned cj = jj - rj * 24u;                // 23
        float dx = rif - (float)rj;
        float dy = cif - (float)cj;
        float w = fmaf(fmaf(ca, dx, cb * dy), dx, cc * (dy * dy));
        float p = EXP2F(w);
        p = fminf(fmaxf(p, EPS_F), 1.0f - EPS_F);
        float num = p * uk;
        float den = (1.0f - p) * (1.0f - uk);
        float r   = den * __builtin_amdgcn_rcpf(num);
        float r2  = r * r;
        float r4  = r2 * r2;
        float r10 = r4 * r4 * r2;
        float res = __builtin_amdgcn_rcpf(1.0f + r10);
        __builtin_nontemporal_store(res, &orow[576]);
    }
}

// ---------------------------------------------------------------------------
extern "C" void kernel_launch(void* const* d_in, const int* in_sizes, int n_in,
                              void* d_out, int out_size, void* d_ws, size_t ws_size,
                              hipStream_t stream) {
    const float* q  = (const float*)d_in[0];
    const float* W1 = (const float*)d_in[1];
    const float* b1 = (const float*)d_in[2];
    const float* W2 = (const float*)d_in[3];
    const float* b2 = (const float*)d_in[4];
    const float* u  = (const float*)d_in[5];
    // d_in[6] = dists: recomputed on the fly, not loaded. d_ws unused.

    fused_mask_kernel<<<NBLOCKS, 256, 0, stream>>>(
        q, W1, b1, W2, b2, u, (float*)d_out);
}